// Round 7
// baseline (897.292 us; speedup 1.0000x reference)
//
#include <hip/hip_runtime.h>

typedef float f4 __attribute__((ext_vector_type(4)));

#define BLK 128
#define NLEV 16
#define NHASH 13        // hashed levels 3..15
#define HSIZE 524288    // 2^19 rows per hashed level
#define HMASK 524287u
#define KOFF3 315475    // first hashed row (= OFFSETS[3])
#define CONV_BLOCKS ((NHASH * HSIZE) / 256)   // 26624, exact

// cumulative level offsets (rows of float2) -- from reference OFFSETS
__constant__ int kOff[NLEV] = {0, 4913, 40850, 315475, 839763, 1364051, 1888339,
                               2412627, 2936915, 3461203, 3985491, 4509779,
                               5034067, 5558355, 6082643, 6606931};

// ---- pre-pass: (a) pack hashed tables to bf16 pairs, (b) pack xs to float4 ----
__global__ __launch_bounds__(256)
void prep_kernel(const float* __restrict__ xs, const float2* __restrict__ tab,
                 unsigned* __restrict__ tbf, f4* __restrict__ xs4, int n)
{
    const int b = blockIdx.x;
    if (b < CONV_BLOCKS) {
        const int i = b * 256 + threadIdx.x;
        float2 v = tab[KOFF3 + i];
        tbf[i] = (__float_as_uint(v.x) >> 16) | (__float_as_uint(v.y) & 0xFFFF0000u);
    } else {
        const int i = (b - CONV_BLOCKS) * 256 + threadIdx.x;
        if (i < n) {
            f4 p;
            p.x = xs[3 * i + 0];
            p.y = xs[3 * i + 1];
            p.z = xs[3 * i + 2];
            p.w = 0.f;
            __builtin_nontemporal_store(p, &xs4[i]);
        }
    }
}

// ---- fused hashed-level passes: blockIdx.y = level-3, 2 points/thread ----
__global__ __launch_bounds__(256)
void levels_kernel(const f4* __restrict__ xs4, const unsigned* __restrict__ tbf,
                   unsigned* __restrict__ scratch, int n)
{
    const int lev = blockIdx.y;
    const int i0  = blockIdx.x * 512 + threadIdx.x;
    const int res = 16 << (3 + lev);
    const float fres = (float)res;
    const unsigned* __restrict__ tl = tbf + (size_t)lev * HSIZE;

    unsigned hx[2], hc[2][4];
    float rx[2], ry[2], rz[2];
    bool valid[2];

    // phase 1: indices + fracs for both points (one dwordx4 load each)
    #pragma unroll
    for (int p = 0; p < 2; ++p) {
        const int i = i0 + p * 256;
        valid[p] = (i < n);
        f4 pt = {0.f, 0.f, 0.f, 0.f};
        if (valid[p]) pt = __builtin_nontemporal_load(&xs4[i]);
        float posx = pt.x * fres, posy = pt.y * fres, posz = pt.z * fres;
        float fxf = floorf(posx), fyf = floorf(posy), fzf = floorf(posz);
        rx[p] = posx - fxf; ry[p] = posy - fyf; rz[p] = posz - fzf;
        // no clamps: frac==0 zeroes the x1 weight at the boundary; indices masked.
        unsigned x  = (unsigned)(int)fxf;
        unsigned y0 = (unsigned)(int)fyf * 2654435761u, y1 = y0 + 2654435761u;
        unsigned z0 = (unsigned)(int)fzf * 805459861u,  z1 = z0 + 805459861u;
        hx[p] = x;
        hc[p][0] = y0 ^ z0; hc[p][1] = y0 ^ z1; hc[p][2] = y1 ^ z0; hc[p][3] = y1 ^ z1;
    }

    // phase 2: gathers. pair-load covers x0 always and x1 when x even
    // (idx(x1) = idx(x0)^1 iff hx even, since x enters the hash with prime 1).
    unsigned va[2][4], vb[2][4];
    #pragma unroll
    for (int p = 0; p < 2; ++p) {
        #pragma unroll
        for (int c = 0; c < 4; ++c) {
            unsigned ia = (hx[p] ^ hc[p][c]) & HMASK;
            uint2 q = *(const uint2*)(tl + (ia & ~1u));
            va[p][c] = (ia & 1u) ? q.y : q.x;
            vb[p][c] = (ia & 1u) ? q.x : q.y;   // correct when hx even
        }
    }
    #pragma unroll
    for (int p = 0; p < 2; ++p) {
        if (hx[p] & 1u) {
            unsigned x1 = hx[p] + 1u;
            #pragma unroll
            for (int c = 0; c < 4; ++c)
                vb[p][c] = tl[(x1 ^ hc[p][c]) & HMASK];
        }
    }

    // phase 3: trilinear + packed bf16 store
    #pragma unroll
    for (int p = 0; p < 2; ++p) {
        if (!valid[p]) continue;
        float wx1 = rx[p], wx0 = 1.f - wx1;
        float wy1 = ry[p], wy0 = 1.f - wy1;
        float wz1 = rz[p], wz0 = 1.f - wz1;
        float wc[4] = {wy0 * wz0, wy0 * wz1, wy1 * wz0, wy1 * wz1};
        float f0 = 0.f, f1 = 0.f;
        #pragma unroll
        for (int c = 0; c < 4; ++c) {
            float a0 = __uint_as_float(va[p][c] << 16);
            float a1 = __uint_as_float(va[p][c] & 0xFFFF0000u);
            float b0 = __uint_as_float(vb[p][c] << 16);
            float b1 = __uint_as_float(vb[p][c] & 0xFFFF0000u);
            f0 += wc[c] * (wx0 * a0 + wx1 * b0);
            f1 += wc[c] * (wx0 * a1 + wx1 * b1);
        }
        unsigned packed = (__float_as_uint(f0) >> 16) | (__float_as_uint(f1) & 0xFFFF0000u);
        __builtin_nontemporal_store(packed, &scratch[(size_t)lev * n + (i0 + p * 256)]);
    }
}

// ---- fallback (ws too small): f32 gathers straight from the input table ----
__global__ __launch_bounds__(256)
void levels_f32_kernel(const float* __restrict__ xs, const float2* __restrict__ tab,
                       unsigned* __restrict__ scratch, int n)
{
    const int lev = blockIdx.y;
    const int i   = blockIdx.x * 256 + threadIdx.x;
    if (i >= n) return;
    const int res = 16 << (3 + lev);
    const float2* __restrict__ tl = tab + kOff[3 + lev];

    const float px = __builtin_nontemporal_load(&xs[3 * i + 0]);
    const float py = __builtin_nontemporal_load(&xs[3 * i + 1]);
    const float pz = __builtin_nontemporal_load(&xs[3 * i + 2]);

    const float fres = (float)res;
    float posx = px * fres, posy = py * fres, posz = pz * fres;
    float fxf = floorf(posx), fyf = floorf(posy), fzf = floorf(posz);
    float rx = posx - fxf, ry = posy - fyf, rz = posz - fzf;

    unsigned hx  = (unsigned)(int)fxf;
    unsigned hy0 = (unsigned)(int)fyf * 2654435761u, hy1 = hy0 + 2654435761u;
    unsigned hz0 = (unsigned)(int)fzf * 805459861u,  hz1 = hz0 + 805459861u;
    unsigned h00 = hy0 ^ hz0, h01 = hy0 ^ hz1, h10 = hy1 ^ hz0, h11 = hy1 ^ hz1;

    unsigned hx1 = hx + 1u;
    float2 v000 = tl[(hx ^ h00) & HMASK], v100 = tl[(hx1 ^ h00) & HMASK];
    float2 v001 = tl[(hx ^ h01) & HMASK], v101 = tl[(hx1 ^ h01) & HMASK];
    float2 v010 = tl[(hx ^ h10) & HMASK], v110 = tl[(hx1 ^ h10) & HMASK];
    float2 v011 = tl[(hx ^ h11) & HMASK], v111 = tl[(hx1 ^ h11) & HMASK];

    float wx1 = rx, wx0 = 1.f - rx;
    float wy1 = ry, wy0 = 1.f - ry;
    float wz1 = rz, wz0 = 1.f - rz;

    float f0, f1, w;
    w = wx0 * wy0 * wz0; f0  = w * v000.x; f1  = w * v000.y;
    w = wx0 * wy0 * wz1; f0 += w * v001.x; f1 += w * v001.y;
    w = wx0 * wy1 * wz0; f0 += w * v010.x; f1 += w * v010.y;
    w = wx0 * wy1 * wz1; f0 += w * v011.x; f1 += w * v011.y;
    w = wx1 * wy0 * wz0; f0 += w * v100.x; f1 += w * v100.y;
    w = wx1 * wy0 * wz1; f0 += w * v101.x; f1 += w * v101.y;
    w = wx1 * wy1 * wz0; f0 += w * v110.x; f1 += w * v110.y;
    w = wx1 * wy1 * wz1; f0 += w * v111.x; f1 += w * v111.y;

    unsigned packed = (__float_as_uint(f0) >> 16) | (__float_as_uint(f1) & 0xFFFF0000u);
    __builtin_nontemporal_store(packed, &scratch[(size_t)lev * n + i]);
}

// ---- final pass: dense levels 0-2 + pos-enc + merge + coalesced write ----
__global__ __launch_bounds__(BLK)
void final_kernel(const f4* __restrict__ xs4, const float* __restrict__ table,
                  const unsigned* __restrict__ scratch, float* __restrict__ out, int n)
{
    __shared__ float sbuf[BLK * 71];
    const int tid  = threadIdx.x;
    const int base = blockIdx.x * BLK;
    const int pi   = base + tid;
    const bool val = (pi < n);

    // issue the 13 scratch loads first (independent; hides latency under dense work)
    unsigned sc[NHASH];
    if (val) {
        #pragma unroll
        for (int h = 0; h < NHASH; ++h)
            sc[h] = __builtin_nontemporal_load(&scratch[(size_t)h * n + pi]);
    }

    f4 pt = {0.f, 0.f, 0.f, 0.f};
    if (val) pt = __builtin_nontemporal_load(&xs4[pi]);
    const float px = pt.x, py = pt.y, pz = pt.z;

    float* srow = sbuf + tid * 71;
    const float2* __restrict__ tab = (const float2*)table;

    // dense levels 0..2 (tables total 2.5 MB -> cache-hot); idx(x1)=idx(x0)+1 always
    #pragma unroll
    for (int l = 0; l < 3; ++l) {
        const int res = 16 << l;
        const float2* __restrict__ tl = tab + kOff[l];
        const float fres = (float)res;

        float posx = px * fres, posy = py * fres, posz = pz * fres;
        float fxf = floorf(posx), fyf = floorf(posy), fzf = floorf(posz);
        float rx = posx - fxf, ry = posy - fyf, rz = posz - fzf;

        const unsigned r1 = (unsigned)(res + 1);
        const unsigned r2 = r1 * r1;
        unsigned x0 = (unsigned)(int)fxf;
        unsigned by0 = (unsigned)(int)fyf * r1; unsigned by1 = by0 + r1;
        unsigned cz0 = (unsigned)(int)fzf * r2; unsigned cz1 = cz0 + r2;

        float2 v000, v001, v010, v011, v100, v101, v110, v111;
        #define PAIRD(B, VA, VB) { \
            unsigned i0 = x0 + (B); \
            if ((i0 & 1u) == 0u) { f4 q = *(const f4*)(tl + i0); \
                VA.x = q.x; VA.y = q.y; VB.x = q.z; VB.y = q.w; } \
            else { VA = tl[i0]; VB = tl[i0 + 1u]; } }
        PAIRD(by0 + cz0, v000, v100)
        PAIRD(by0 + cz1, v001, v101)
        PAIRD(by1 + cz0, v010, v110)
        PAIRD(by1 + cz1, v011, v111)
        #undef PAIRD

        float wx1 = rx, wx0 = 1.f - rx;
        float wy1 = ry, wy0 = 1.f - ry;
        float wz1 = rz, wz0 = 1.f - rz;

        float f0, f1, w;
        w = wx0 * wy0 * wz0; f0  = w * v000.x; f1  = w * v000.y;
        w = wx0 * wy0 * wz1; f0 += w * v001.x; f1 += w * v001.y;
        w = wx0 * wy1 * wz0; f0 += w * v010.x; f1 += w * v010.y;
        w = wx0 * wy1 * wz1; f0 += w * v011.x; f1 += w * v011.y;
        w = wx1 * wy0 * wz0; f0 += w * v100.x; f1 += w * v100.y;
        w = wx1 * wy0 * wz1; f0 += w * v101.x; f1 += w * v101.y;
        w = wx1 * wy1 * wz0; f0 += w * v110.x; f1 += w * v110.y;
        w = wx1 * wy1 * wz1; f0 += w * v111.x; f1 += w * v111.y;

        srow[2 * l]     = f0;
        srow[2 * l + 1] = f1;
    }

    // hashed levels 3..15 (already loaded)
    #pragma unroll
    for (int h = 0; h < NHASH; ++h) {
        srow[6 + 2 * h] = __uint_as_float(sc[h] << 16);
        srow[7 + 2 * h] = __uint_as_float(sc[h] & 0xFFFF0000u);
    }

    // positional encoding via double-angle recurrence:
    // sin(2a)=2 sin a cos a, cos(2a)=1-2 sin^2 a  (coeffs are exactly 2^f)
    srow[32] = px; srow[33] = py; srow[34] = pz;
    float sx, cx, sy, cy, sz, cz;
    __sincosf(px, &sx, &cx);
    __sincosf(py, &sy, &cy);
    __sincosf(pz, &sz, &cz);
    #pragma unroll
    for (int f = 0; f < 6; ++f) {
        srow[35 + 6*f + 0] = sx; srow[35 + 6*f + 3] = cx;
        srow[35 + 6*f + 1] = sy; srow[35 + 6*f + 4] = cy;
        srow[35 + 6*f + 2] = sz; srow[35 + 6*f + 5] = cz;
        if (f < 5) {
            float nsx = 2.f * sx * cx, ncx = 1.f - 2.f * sx * sx;
            float nsy = 2.f * sy * cy, ncy = 1.f - 2.f * sy * sy;
            float nsz = 2.f * sz * cz, ncz = 1.f - 2.f * sz * sz;
            sx = nsx; cx = ncx; sy = nsy; cy = ncy; sz = nsz; cz = ncz;
        }
    }

    __syncthreads();

    const int nvalid = min(BLK, n - base);
    float* obase = out + (size_t)base * 71;
    if (nvalid == BLK) {
        f4* o4 = (f4*)obase;
        const f4* s4 = (const f4*)sbuf;
        #pragma unroll 1
        for (int i = tid; i < (BLK * 71) / 4; i += BLK)
            __builtin_nontemporal_store(s4[i], &o4[i]);
    } else {
        #pragma unroll 1
        for (int i = tid; i < nvalid * 71; i += BLK)
            __builtin_nontemporal_store(sbuf[i], &obase[i]);
    }
}

// fallback final (reads raw xs) for the ws-less path
__global__ __launch_bounds__(BLK)
void final_f32_kernel(const float* __restrict__ xs, const float* __restrict__ table,
                      const unsigned* __restrict__ scratch, float* __restrict__ out, int n)
{
    __shared__ float sbuf[BLK * 71];
    const int tid  = threadIdx.x;
    const int base = blockIdx.x * BLK;
    const int pi   = base + tid;

    float px = 0.f, py = 0.f, pz = 0.f;
    if (pi < n) { px = xs[3*pi]; py = xs[3*pi+1]; pz = xs[3*pi+2]; }

    float* srow = sbuf + tid * 71;
    const float2* __restrict__ tab = (const float2*)table;

    #pragma unroll
    for (int l = 0; l < 3; ++l) {
        const int res = 16 << l;
        const float2* __restrict__ tl = tab + kOff[l];
        const float fres = (float)res;
        float posx = px * fres, posy = py * fres, posz = pz * fres;
        float fxf = floorf(posx), fyf = floorf(posy), fzf = floorf(posz);
        float rx = posx - fxf, ry = posy - fyf, rz = posz - fzf;
        const unsigned r1 = (unsigned)(res + 1), r2 = r1 * r1;
        unsigned x0 = (unsigned)(int)fxf;
        unsigned by0 = (unsigned)(int)fyf * r1, by1 = by0 + r1;
        unsigned cz0 = (unsigned)(int)fzf * r2, cz1 = cz0 + r2;
        float2 v000 = tl[x0+by0+cz0], v100 = tl[x0+by0+cz0+1];
        float2 v001 = tl[x0+by0+cz1], v101 = tl[x0+by0+cz1+1];
        float2 v010 = tl[x0+by1+cz0], v110 = tl[x0+by1+cz0+1];
        float2 v011 = tl[x0+by1+cz1], v111 = tl[x0+by1+cz1+1];
        float wx1 = rx, wx0 = 1.f - rx, wy1 = ry, wy0 = 1.f - ry, wz1 = rz, wz0 = 1.f - rz;
        float f0, f1, w;
        w = wx0*wy0*wz0; f0  = w*v000.x; f1  = w*v000.y;
        w = wx0*wy0*wz1; f0 += w*v001.x; f1 += w*v001.y;
        w = wx0*wy1*wz0; f0 += w*v010.x; f1 += w*v010.y;
        w = wx0*wy1*wz1; f0 += w*v011.x; f1 += w*v011.y;
        w = wx1*wy0*wz0; f0 += w*v100.x; f1 += w*v100.y;
        w = wx1*wy0*wz1; f0 += w*v101.x; f1 += w*v101.y;
        w = wx1*wy1*wz0; f0 += w*v110.x; f1 += w*v110.y;
        w = wx1*wy1*wz1; f0 += w*v111.x; f1 += w*v111.y;
        srow[2*l] = f0; srow[2*l+1] = f1;
    }
    if (pi < n) {
        #pragma unroll
        for (int h = 0; h < NHASH; ++h) {
            unsigned u = __builtin_nontemporal_load(&scratch[(size_t)h * n + pi]);
            srow[6+2*h] = __uint_as_float(u << 16);
            srow[7+2*h] = __uint_as_float(u & 0xFFFF0000u);
        }
    }
    srow[32] = px; srow[33] = py; srow[34] = pz;
    float coef = 1.f;
    #pragma unroll
    for (int f = 0; f < 6; ++f) {
        float s, c;
        __sincosf(px*coef, &s, &c); srow[35+6*f+0] = s; srow[35+6*f+3] = c;
        __sincosf(py*coef, &s, &c); srow[35+6*f+1] = s; srow[35+6*f+4] = c;
        __sincosf(pz*coef, &s, &c); srow[35+6*f+2] = s; srow[35+6*f+5] = c;
        coef *= 2.f;
    }
    __syncthreads();
    const int nvalid = min(BLK, n - base);
    float* obase = out + (size_t)base * 71;
    if (nvalid == BLK) {
        f4* o4 = (f4*)obase;
        const f4* s4 = (const f4*)sbuf;
        #pragma unroll 1
        for (int i = tid; i < (BLK * 71) / 4; i += BLK)
            __builtin_nontemporal_store(s4[i], &o4[i]);
    } else {
        #pragma unroll 1
        for (int i = tid; i < nvalid * 71; i += BLK)
            __builtin_nontemporal_store(sbuf[i], &obase[i]);
    }
}

extern "C" void kernel_launch(void* const* d_in, const int* in_sizes, int n_in,
                              void* d_out, int out_size, void* d_ws, size_t ws_size,
                              hipStream_t stream) {
    const float* xs    = (const float*)d_in[0];
    const float* table = (const float*)d_in[1];
    float* out = (float*)d_out;
    const int n = in_sizes[0] / 3;          // 2,000,000 points

    unsigned* scratch = (unsigned*)d_ws;                       // 13*n*4 = 104 MB
    const size_t featBytes = (size_t)NHASH * (size_t)n * 4u;
    const size_t tblBytes  = (size_t)NHASH * HSIZE * 4u;       // 27.3 MB
    const size_t xs4Bytes  = (size_t)n * 16u;                  // 32 MB
    const float2* tab = (const float2*)table;
    const int gf = (n + BLK - 1) / BLK;

    if (ws_size >= featBytes + tblBytes + xs4Bytes) {
        unsigned* tbf = (unsigned*)((char*)d_ws + featBytes);
        f4* xs4 = (f4*)((char*)d_ws + featBytes + tblBytes);

        const int packBlocks = (n + 255) / 256;
        hipLaunchKernelGGL(prep_kernel, dim3(CONV_BLOCKS + packBlocks), dim3(256),
                           0, stream, xs, tab, tbf, xs4, n);

        const int bpl = (n + 511) / 512;
        hipLaunchKernelGGL(levels_kernel, dim3(bpl, NHASH), dim3(256), 0, stream,
                           xs4, tbf, scratch, n);
        hipLaunchKernelGGL(final_kernel, dim3(gf), dim3(BLK), 0, stream,
                           xs4, table, scratch, out, n);
    } else {
        const int bpl = (n + 255) / 256;
        hipLaunchKernelGGL(levels_f32_kernel, dim3(bpl, NHASH), dim3(256), 0, stream,
                           xs, tab, scratch, n);
        hipLaunchKernelGGL(final_f32_kernel, dim3(gf), dim3(BLK), 0, stream,
                           xs, table, scratch, out, n);
    }
}

// Round 8
// 882.443 us; speedup vs baseline: 1.0168x; 1.0168x over previous
//
#include <hip/hip_runtime.h>

typedef float f4 __attribute__((ext_vector_type(4)));

#define BLK 128
#define NLEV 16
#define NHASH 13        // hashed levels 3..15
#define HSIZE 524288    // 2^19 rows per hashed level
#define HMASK 524287u
#define KOFF3 315475    // first hashed row (= OFFSETS[3])
#define SROW 36         // staged floats/pt in final: 32 feats + xyz (+pad)
#define CONV_BLOCKS ((NHASH * HSIZE) / 256)   // 26624, exact

// cumulative level offsets (rows of float2) -- from reference OFFSETS
__constant__ int kOff[NLEV] = {0, 4913, 40850, 315475, 839763, 1364051, 1888339,
                               2412627, 2936915, 3461203, 3985491, 4509779,
                               5034067, 5558355, 6082643, 6606931};

// ---- pre-pass: (a) pack hashed tables to bf16 pairs, (b) pack xs to float4 ----
__global__ __launch_bounds__(256)
void prep_kernel(const float* __restrict__ xs, const float2* __restrict__ tab,
                 unsigned* __restrict__ tbf, f4* __restrict__ xs4, int n)
{
    const int b = blockIdx.x;
    if (b < CONV_BLOCKS) {
        const int i = b * 256 + threadIdx.x;
        float2 v = tab[KOFF3 + i];
        tbf[i] = (__float_as_uint(v.x) >> 16) | (__float_as_uint(v.y) & 0xFFFF0000u);
    } else {
        const int i = (b - CONV_BLOCKS) * 256 + threadIdx.x;
        if (i < n) {
            f4 p;
            p.x = xs[3 * i + 0];
            p.y = xs[3 * i + 1];
            p.z = xs[3 * i + 2];
            p.w = 0.f;
            __builtin_nontemporal_store(p, &xs4[i]);
        }
    }
}

// ---- fused hashed-level passes: blockIdx.y = level-3, 2 points/thread ----
// Bound by random line-request rate into L2 (~12/cyc/XCD); request count is at
// the algorithmic floor (avg 6 lines/pt/level given the Instant-NGP hash).
__global__ __launch_bounds__(256)
void levels_kernel(const f4* __restrict__ xs4, const unsigned* __restrict__ tbf,
                   unsigned* __restrict__ scratch, int n)
{
    const int lev = blockIdx.y;
    const int i0  = blockIdx.x * 512 + threadIdx.x;
    const int res = 16 << (3 + lev);
    const float fres = (float)res;
    const unsigned* __restrict__ tl = tbf + (size_t)lev * HSIZE;

    unsigned hx[2], hc[2][4];
    float rx[2], ry[2], rz[2];
    bool valid[2];

    // phase 1: indices + fracs for both points (one dwordx4 load each; plain
    // load so the 13x-reread xs4 stream stays L3-resident)
    #pragma unroll
    for (int p = 0; p < 2; ++p) {
        const int i = i0 + p * 256;
        valid[p] = (i < n);
        f4 pt = {0.f, 0.f, 0.f, 0.f};
        if (valid[p]) pt = xs4[i];
        float posx = pt.x * fres, posy = pt.y * fres, posz = pt.z * fres;
        float fxf = floorf(posx), fyf = floorf(posy), fzf = floorf(posz);
        rx[p] = posx - fxf; ry[p] = posy - fyf; rz[p] = posz - fzf;
        // no clamps: frac==0 zeroes the x1 weight at the boundary; indices masked.
        unsigned x  = (unsigned)(int)fxf;
        unsigned y0 = (unsigned)(int)fyf * 2654435761u, y1 = y0 + 2654435761u;
        unsigned z0 = (unsigned)(int)fzf * 805459861u,  z1 = z0 + 805459861u;
        hx[p] = x;
        hc[p][0] = y0 ^ z0; hc[p][1] = y0 ^ z1; hc[p][2] = y1 ^ z0; hc[p][3] = y1 ^ z1;
    }

    // phase 2: gathers. pair-load covers x0 always and x1 when x even
    // (idx(x1) = idx(x0)^1 iff hx even, since x enters the hash with prime 1).
    unsigned va[2][4], vb[2][4];
    #pragma unroll
    for (int p = 0; p < 2; ++p) {
        #pragma unroll
        for (int c = 0; c < 4; ++c) {
            unsigned ia = (hx[p] ^ hc[p][c]) & HMASK;
            uint2 q = *(const uint2*)(tl + (ia & ~1u));
            va[p][c] = (ia & 1u) ? q.y : q.x;
            vb[p][c] = (ia & 1u) ? q.x : q.y;   // correct when hx even
        }
    }
    #pragma unroll
    for (int p = 0; p < 2; ++p) {
        if (hx[p] & 1u) {
            unsigned x1 = hx[p] + 1u;
            #pragma unroll
            for (int c = 0; c < 4; ++c)
                vb[p][c] = tl[(x1 ^ hc[p][c]) & HMASK];
        }
    }

    // phase 3: trilinear + packed bf16 store
    #pragma unroll
    for (int p = 0; p < 2; ++p) {
        if (!valid[p]) continue;
        float wx1 = rx[p], wx0 = 1.f - wx1;
        float wy1 = ry[p], wy0 = 1.f - wy1;
        float wz1 = rz[p], wz0 = 1.f - wz1;
        float wc[4] = {wy0 * wz0, wy0 * wz1, wy1 * wz0, wy1 * wz1};
        float f0 = 0.f, f1 = 0.f;
        #pragma unroll
        for (int c = 0; c < 4; ++c) {
            float a0 = __uint_as_float(va[p][c] << 16);
            float a1 = __uint_as_float(va[p][c] & 0xFFFF0000u);
            float b0 = __uint_as_float(vb[p][c] << 16);
            float b1 = __uint_as_float(vb[p][c] & 0xFFFF0000u);
            f0 += wc[c] * (wx0 * a0 + wx1 * b0);
            f1 += wc[c] * (wx0 * a1 + wx1 * b1);
        }
        unsigned packed = (__float_as_uint(f0) >> 16) | (__float_as_uint(f1) & 0xFFFF0000u);
        __builtin_nontemporal_store(packed, &scratch[(size_t)lev * n + (i0 + p * 256)]);
    }
}

// ---- fallback (ws too small): f32 gathers straight from the input table ----
__global__ __launch_bounds__(256)
void levels_f32_kernel(const float* __restrict__ xs, const float2* __restrict__ tab,
                       unsigned* __restrict__ scratch, int n)
{
    const int lev = blockIdx.y;
    const int i   = blockIdx.x * 256 + threadIdx.x;
    if (i >= n) return;
    const int res = 16 << (3 + lev);
    const float2* __restrict__ tl = tab + kOff[3 + lev];

    const float px = __builtin_nontemporal_load(&xs[3 * i + 0]);
    const float py = __builtin_nontemporal_load(&xs[3 * i + 1]);
    const float pz = __builtin_nontemporal_load(&xs[3 * i + 2]);

    const float fres = (float)res;
    float posx = px * fres, posy = py * fres, posz = pz * fres;
    float fxf = floorf(posx), fyf = floorf(posy), fzf = floorf(posz);
    float rx = posx - fxf, ry = posy - fyf, rz = posz - fzf;

    unsigned hx  = (unsigned)(int)fxf;
    unsigned hy0 = (unsigned)(int)fyf * 2654435761u, hy1 = hy0 + 2654435761u;
    unsigned hz0 = (unsigned)(int)fzf * 805459861u,  hz1 = hz0 + 805459861u;
    unsigned h00 = hy0 ^ hz0, h01 = hy0 ^ hz1, h10 = hy1 ^ hz0, h11 = hy1 ^ hz1;

    unsigned hx1 = hx + 1u;
    float2 v000 = tl[(hx ^ h00) & HMASK], v100 = tl[(hx1 ^ h00) & HMASK];
    float2 v001 = tl[(hx ^ h01) & HMASK], v101 = tl[(hx1 ^ h01) & HMASK];
    float2 v010 = tl[(hx ^ h10) & HMASK], v110 = tl[(hx1 ^ h10) & HMASK];
    float2 v011 = tl[(hx ^ h11) & HMASK], v111 = tl[(hx1 ^ h11) & HMASK];

    float wx1 = rx, wx0 = 1.f - rx;
    float wy1 = ry, wy0 = 1.f - ry;
    float wz1 = rz, wz0 = 1.f - rz;

    float f0, f1, w;
    w = wx0 * wy0 * wz0; f0  = w * v000.x; f1  = w * v000.y;
    w = wx0 * wy0 * wz1; f0 += w * v001.x; f1 += w * v001.y;
    w = wx0 * wy1 * wz0; f0 += w * v010.x; f1 += w * v010.y;
    w = wx0 * wy1 * wz1; f0 += w * v011.x; f1 += w * v011.y;
    w = wx1 * wy0 * wz0; f0 += w * v100.x; f1 += w * v100.y;
    w = wx1 * wy0 * wz1; f0 += w * v101.x; f1 += w * v101.y;
    w = wx1 * wy1 * wz0; f0 += w * v110.x; f1 += w * v110.y;
    w = wx1 * wy1 * wz1; f0 += w * v111.x; f1 += w * v111.y;

    unsigned packed = (__float_as_uint(f0) >> 16) | (__float_as_uint(f1) & 0xFFFF0000u);
    __builtin_nontemporal_store(packed, &scratch[(size_t)lev * n + i]);
}

// ---- final pass: dense levels 0-2 + merge + pos-enc-on-writeout ----
// LDS = BLK*36 floats (18 KB) -> 8 blocks/CU (50% occupancy). Trig is computed
// during the coalesced writeout (VALU idle there); output cols [35,71) decode
// to sin/cos(xyz * 2^freq).
__global__ __launch_bounds__(BLK)
void final_kernel(const f4* __restrict__ xs4, const float* __restrict__ table,
                  const unsigned* __restrict__ scratch, float* __restrict__ out, int n)
{
    __shared__ float sbuf[BLK * SROW];
    const int tid  = threadIdx.x;
    const int base = blockIdx.x * BLK;
    const int pi   = base + tid;
    const bool val = (pi < n);

    // issue the 13 scratch loads first (independent; hides latency under dense work)
    unsigned sc[NHASH];
    if (val) {
        #pragma unroll
        for (int h = 0; h < NHASH; ++h)
            sc[h] = __builtin_nontemporal_load(&scratch[(size_t)h * n + pi]);
    }

    f4 pt = {0.f, 0.f, 0.f, 0.f};
    if (val) pt = __builtin_nontemporal_load(&xs4[pi]);
    const float px = pt.x, py = pt.y, pz = pt.z;

    float* srow = sbuf + tid * SROW;
    const float2* __restrict__ tab = (const float2*)table;

    // dense levels 0..2 (tables total 2.5 MB -> cache-hot); idx(x1)=idx(x0)+1 always
    #pragma unroll
    for (int l = 0; l < 3; ++l) {
        const int res = 16 << l;
        const float2* __restrict__ tl = tab + kOff[l];
        const float fres = (float)res;

        float posx = px * fres, posy = py * fres, posz = pz * fres;
        float fxf = floorf(posx), fyf = floorf(posy), fzf = floorf(posz);
        float rx = posx - fxf, ry = posy - fyf, rz = posz - fzf;

        const unsigned r1 = (unsigned)(res + 1);
        const unsigned r2 = r1 * r1;
        unsigned x0 = (unsigned)(int)fxf;
        unsigned by0 = (unsigned)(int)fyf * r1; unsigned by1 = by0 + r1;
        unsigned cz0 = (unsigned)(int)fzf * r2; unsigned cz1 = cz0 + r2;

        float2 v000, v001, v010, v011, v100, v101, v110, v111;
        #define PAIRD(B, VA, VB) { \
            unsigned i0 = x0 + (B); \
            if ((i0 & 1u) == 0u) { f4 q = *(const f4*)(tl + i0); \
                VA.x = q.x; VA.y = q.y; VB.x = q.z; VB.y = q.w; } \
            else { VA = tl[i0]; VB = tl[i0 + 1u]; } }
        PAIRD(by0 + cz0, v000, v100)
        PAIRD(by0 + cz1, v001, v101)
        PAIRD(by1 + cz0, v010, v110)
        PAIRD(by1 + cz1, v011, v111)
        #undef PAIRD

        float wx1 = rx, wx0 = 1.f - rx;
        float wy1 = ry, wy0 = 1.f - ry;
        float wz1 = rz, wz0 = 1.f - rz;

        float f0, f1, w;
        w = wx0 * wy0 * wz0; f0  = w * v000.x; f1  = w * v000.y;
        w = wx0 * wy0 * wz1; f0 += w * v001.x; f1 += w * v001.y;
        w = wx0 * wy1 * wz0; f0 += w * v010.x; f1 += w * v010.y;
        w = wx0 * wy1 * wz1; f0 += w * v011.x; f1 += w * v011.y;
        w = wx1 * wy0 * wz0; f0 += w * v100.x; f1 += w * v100.y;
        w = wx1 * wy0 * wz1; f0 += w * v101.x; f1 += w * v101.y;
        w = wx1 * wy1 * wz0; f0 += w * v110.x; f1 += w * v110.y;
        w = wx1 * wy1 * wz1; f0 += w * v111.x; f1 += w * v111.y;

        srow[2 * l]     = f0;
        srow[2 * l + 1] = f1;
    }

    // hashed levels 3..15 (already loaded)
    #pragma unroll
    for (int h = 0; h < NHASH; ++h) {
        srow[6 + 2 * h] = __uint_as_float(sc[h] << 16);
        srow[7 + 2 * h] = __uint_as_float(sc[h] & 0xFFFF0000u);
    }
    srow[32] = px; srow[33] = py; srow[34] = pz;

    __syncthreads();

    // coalesced writeout; cols [35,71): g=f-35, freq=g/6, r=g%6,
    // val = (r<3 ? sin : cos)(xyz[r%3] * 2^freq)
    const int nvalid = min(BLK, n - base);
    float* obase = out + (size_t)base * 71;
    if (nvalid == BLK) {
        f4* o4 = (f4*)obase;
        #pragma unroll 1
        for (int i = tid; i < (BLK * 71) / 4; i += BLK) {
            const int e = 4 * i;
            f4 v;
            #pragma unroll
            for (int j = 0; j < 4; ++j) {
                const int ee = e + j;
                const int p = ee / 71;
                const int f = ee - p * 71;
                float valf;
                if (f < 35) {
                    valf = sbuf[p * SROW + f];
                } else {
                    const int g = f - 35;
                    const int freq = g / 6;
                    const int r = g - 6 * freq;
                    const int dim = (r < 3) ? r : r - 3;
                    const float a = sbuf[p * SROW + 32 + dim] * (float)(1 << freq);
                    float s, c;
                    __sincosf(a, &s, &c);
                    valf = (r < 3) ? s : c;
                }
                v[j] = valf;
            }
            __builtin_nontemporal_store(v, &o4[i]);
        }
    } else {
        #pragma unroll 1
        for (int i = tid; i < nvalid * 71; i += BLK) {
            const int p = i / 71;
            const int f = i - p * 71;
            float valf;
            if (f < 35) {
                valf = sbuf[p * SROW + f];
            } else {
                const int g = f - 35;
                const int freq = g / 6;
                const int r = g - 6 * freq;
                const int dim = (r < 3) ? r : r - 3;
                const float a = sbuf[p * SROW + 32 + dim] * (float)(1 << freq);
                float s, c;
                __sincosf(a, &s, &c);
                valf = (r < 3) ? s : c;
            }
            __builtin_nontemporal_store(valf, &obase[i]);
        }
    }
}

// fallback final (reads raw xs) for the ws-less path
__global__ __launch_bounds__(BLK)
void final_f32_kernel(const float* __restrict__ xs, const float* __restrict__ table,
                      const unsigned* __restrict__ scratch, float* __restrict__ out, int n)
{
    __shared__ float sbuf[BLK * SROW];
    const int tid  = threadIdx.x;
    const int base = blockIdx.x * BLK;
    const int pi   = base + tid;

    float px = 0.f, py = 0.f, pz = 0.f;
    if (pi < n) { px = xs[3*pi]; py = xs[3*pi+1]; pz = xs[3*pi+2]; }

    float* srow = sbuf + tid * SROW;
    const float2* __restrict__ tab = (const float2*)table;

    #pragma unroll
    for (int l = 0; l < 3; ++l) {
        const int res = 16 << l;
        const float2* __restrict__ tl = tab + kOff[l];
        const float fres = (float)res;
        float posx = px * fres, posy = py * fres, posz = pz * fres;
        float fxf = floorf(posx), fyf = floorf(posy), fzf = floorf(posz);
        float rx = posx - fxf, ry = posy - fyf, rz = posz - fzf;
        const unsigned r1 = (unsigned)(res + 1), r2 = r1 * r1;
        unsigned x0 = (unsigned)(int)fxf;
        unsigned by0 = (unsigned)(int)fyf * r1, by1 = by0 + r1;
        unsigned cz0 = (unsigned)(int)fzf * r2, cz1 = cz0 + r2;
        float2 v000 = tl[x0+by0+cz0], v100 = tl[x0+by0+cz0+1];
        float2 v001 = tl[x0+by0+cz1], v101 = tl[x0+by0+cz1+1];
        float2 v010 = tl[x0+by1+cz0], v110 = tl[x0+by1+cz0+1];
        float2 v011 = tl[x0+by1+cz1], v111 = tl[x0+by1+cz1+1];
        float wx1 = rx, wx0 = 1.f - rx, wy1 = ry, wy0 = 1.f - ry, wz1 = rz, wz0 = 1.f - rz;
        float f0, f1, w;
        w = wx0*wy0*wz0; f0  = w*v000.x; f1  = w*v000.y;
        w = wx0*wy0*wz1; f0 += w*v001.x; f1 += w*v001.y;
        w = wx0*wy1*wz0; f0 += w*v010.x; f1 += w*v010.y;
        w = wx0*wy1*wz1; f0 += w*v011.x; f1 += w*v011.y;
        w = wx1*wy0*wz0; f0 += w*v100.x; f1 += w*v100.y;
        w = wx1*wy0*wz1; f0 += w*v101.x; f1 += w*v101.y;
        w = wx1*wy1*wz0; f0 += w*v110.x; f1 += w*v110.y;
        w = wx1*wy1*wz1; f0 += w*v111.x; f1 += w*v111.y;
        srow[2*l] = f0; srow[2*l+1] = f1;
    }
    if (pi < n) {
        #pragma unroll
        for (int h = 0; h < NHASH; ++h) {
            unsigned u = __builtin_nontemporal_load(&scratch[(size_t)h * n + pi]);
            srow[6+2*h] = __uint_as_float(u << 16);
            srow[7+2*h] = __uint_as_float(u & 0xFFFF0000u);
        }
    }
    srow[32] = px; srow[33] = py; srow[34] = pz;
    __syncthreads();
    const int nvalid = min(BLK, n - base);
    float* obase = out + (size_t)base * 71;
    #pragma unroll 1
    for (int i = tid; i < nvalid * 71; i += BLK) {
        const int p = i / 71;
        const int f = i - p * 71;
        float valf;
        if (f < 35) {
            valf = sbuf[p * SROW + f];
        } else {
            const int g = f - 35;
            const int freq = g / 6;
            const int r = g - 6 * freq;
            const int dim = (r < 3) ? r : r - 3;
            const float a = sbuf[p * SROW + 32 + dim] * (float)(1 << freq);
            float s, c;
            __sincosf(a, &s, &c);
            valf = (r < 3) ? s : c;
        }
        __builtin_nontemporal_store(valf, &obase[i]);
    }
}

extern "C" void kernel_launch(void* const* d_in, const int* in_sizes, int n_in,
                              void* d_out, int out_size, void* d_ws, size_t ws_size,
                              hipStream_t stream) {
    const float* xs    = (const float*)d_in[0];
    const float* table = (const float*)d_in[1];
    float* out = (float*)d_out;
    const int n = in_sizes[0] / 3;          // 2,000,000 points

    unsigned* scratch = (unsigned*)d_ws;                       // 13*n*4 = 104 MB
    const size_t featBytes = (size_t)NHASH * (size_t)n * 4u;
    const size_t tblBytes  = (size_t)NHASH * HSIZE * 4u;       // 27.3 MB
    const size_t xs4Bytes  = (size_t)n * 16u;                  // 32 MB
    const float2* tab = (const float2*)table;
    const int gf = (n + BLK - 1) / BLK;

    if (ws_size >= featBytes + tblBytes + xs4Bytes) {
        unsigned* tbf = (unsigned*)((char*)d_ws + featBytes);
        f4* xs4 = (f4*)((char*)d_ws + featBytes + tblBytes);

        const int packBlocks = (n + 255) / 256;
        hipLaunchKernelGGL(prep_kernel, dim3(CONV_BLOCKS + packBlocks), dim3(256),
                           0, stream, xs, tab, tbf, xs4, n);

        const int bpl = (n + 511) / 512;
        hipLaunchKernelGGL(levels_kernel, dim3(bpl, NHASH), dim3(256), 0, stream,
                           xs4, tbf, scratch, n);
        hipLaunchKernelGGL(final_kernel, dim3(gf), dim3(BLK), 0, stream,
                           xs4, table, scratch, out, n);
    } else {
        const int bpl = (n + 255) / 256;
        hipLaunchKernelGGL(levels_f32_kernel, dim3(bpl, NHASH), dim3(256), 0, stream,
                           xs, tab, scratch, n);
        hipLaunchKernelGGL(final_f32_kernel, dim3(gf), dim3(BLK), 0, stream,
                           xs, table, scratch, out, n);
    }
}

// Round 9
// 777.630 us; speedup vs baseline: 1.1539x; 1.1348x over previous
//
#include <hip/hip_runtime.h>

typedef float f4 __attribute__((ext_vector_type(4)));

#define BLK 128
#define NLEV 16
#define NHASH 13        // hashed levels 3..15
#define HSIZE 524288    // 2^19 rows per hashed level
#define HMASK 524287u
#define KOFF3 315475    // first hashed row (= OFFSETS[3])
#define SROW 36         // staged floats/pt in final: 32 feats + xyz (+pad)
#define CONV_BLOCKS ((NHASH * HSIZE) / 256)   // 26624, exact

// cumulative level offsets (rows of float2) -- from reference OFFSETS
__constant__ int kOff[NLEV] = {0, 4913, 40850, 315475, 839763, 1364051, 1888339,
                               2412627, 2936915, 3461203, 3985491, 4509779,
                               5034067, 5558355, 6082643, 6606931};

// ---- pre-pass: (a) pack hashed tables to bf16 pairs, (b) pack xs to float4 ----
__global__ __launch_bounds__(256)
void prep_kernel(const float* __restrict__ xs, const float2* __restrict__ tab,
                 unsigned* __restrict__ tbf, f4* __restrict__ xs4, int n)
{
    const int b = blockIdx.x;
    if (b < CONV_BLOCKS) {
        const int i = b * 256 + threadIdx.x;
        float2 v = tab[KOFF3 + i];
        tbf[i] = (__float_as_uint(v.x) >> 16) | (__float_as_uint(v.y) & 0xFFFF0000u);
    } else {
        const int i = (b - CONV_BLOCKS) * 256 + threadIdx.x;
        if (i < n) {
            f4 p;
            p.x = xs[3 * i + 0];
            p.y = xs[3 * i + 1];
            p.z = xs[3 * i + 2];
            p.w = 0.f;
            p = p;  // keep
            xs4[i] = p;     // plain store -> stays in L3 for the 14 re-reads
        }
    }
}

// ---- fused hashed-level passes: blockIdx.y = level-3, 2 points/thread ----
// At the L2 random-line-request cap (~12.5/cyc/XCD); request count is at the
// algorithmic floor (avg 6 lines/pt/level given the Instant-NGP hash).
__global__ __launch_bounds__(256)
void levels_kernel(const f4* __restrict__ xs4, const unsigned* __restrict__ tbf,
                   unsigned* __restrict__ scratch, int n)
{
    const int lev = blockIdx.y;
    const int i0  = blockIdx.x * 512 + threadIdx.x;
    const int res = 16 << (3 + lev);
    const float fres = (float)res;
    const unsigned* __restrict__ tl = tbf + (size_t)lev * HSIZE;

    unsigned hx[2], hc[2][4];
    float rx[2], ry[2], rz[2];
    bool valid[2];

    // phase 1: indices + fracs for both points (one dwordx4 load each)
    #pragma unroll
    for (int p = 0; p < 2; ++p) {
        const int i = i0 + p * 256;
        valid[p] = (i < n);
        f4 pt = {0.f, 0.f, 0.f, 0.f};
        if (valid[p]) pt = xs4[i];
        float posx = pt.x * fres, posy = pt.y * fres, posz = pt.z * fres;
        float fxf = floorf(posx), fyf = floorf(posy), fzf = floorf(posz);
        rx[p] = posx - fxf; ry[p] = posy - fyf; rz[p] = posz - fzf;
        // no clamps: frac==0 zeroes the x1 weight at the boundary; indices masked.
        unsigned x  = (unsigned)(int)fxf;
        unsigned y0 = (unsigned)(int)fyf * 2654435761u, y1 = y0 + 2654435761u;
        unsigned z0 = (unsigned)(int)fzf * 805459861u,  z1 = z0 + 805459861u;
        hx[p] = x;
        hc[p][0] = y0 ^ z0; hc[p][1] = y0 ^ z1; hc[p][2] = y1 ^ z0; hc[p][3] = y1 ^ z1;
    }

    // phase 2: gathers. pair-load covers x0 always and x1 when x even
    // (idx(x1) = idx(x0)^1 iff hx even, since x enters the hash with prime 1).
    unsigned va[2][4], vb[2][4];
    #pragma unroll
    for (int p = 0; p < 2; ++p) {
        #pragma unroll
        for (int c = 0; c < 4; ++c) {
            unsigned ia = (hx[p] ^ hc[p][c]) & HMASK;
            uint2 q = *(const uint2*)(tl + (ia & ~1u));
            va[p][c] = (ia & 1u) ? q.y : q.x;
            vb[p][c] = (ia & 1u) ? q.x : q.y;   // correct when hx even
        }
    }
    #pragma unroll
    for (int p = 0; p < 2; ++p) {
        if (hx[p] & 1u) {
            unsigned x1 = hx[p] + 1u;
            #pragma unroll
            for (int c = 0; c < 4; ++c)
                vb[p][c] = tl[(x1 ^ hc[p][c]) & HMASK];
        }
    }

    // phase 3: trilinear + packed bf16 store (plain store -> L2/L3 resident
    // for final's re-read; levels is request-bound so eviction pressure is free)
    #pragma unroll
    for (int p = 0; p < 2; ++p) {
        if (!valid[p]) continue;
        float wx1 = rx[p], wx0 = 1.f - wx1;
        float wy1 = ry[p], wy0 = 1.f - wy1;
        float wz1 = rz[p], wz0 = 1.f - wz1;
        float wc[4] = {wy0 * wz0, wy0 * wz1, wy1 * wz0, wy1 * wz1};
        float f0 = 0.f, f1 = 0.f;
        #pragma unroll
        for (int c = 0; c < 4; ++c) {
            float a0 = __uint_as_float(va[p][c] << 16);
            float a1 = __uint_as_float(va[p][c] & 0xFFFF0000u);
            float b0 = __uint_as_float(vb[p][c] << 16);
            float b1 = __uint_as_float(vb[p][c] & 0xFFFF0000u);
            f0 += wc[c] * (wx0 * a0 + wx1 * b0);
            f1 += wc[c] * (wx0 * a1 + wx1 * b1);
        }
        unsigned packed = (__float_as_uint(f0) >> 16) | (__float_as_uint(f1) & 0xFFFF0000u);
        scratch[(size_t)lev * n + (i0 + p * 256)] = packed;
    }
}

// ---- fallback (ws too small): f32 gathers straight from the input table ----
__global__ __launch_bounds__(256)
void levels_f32_kernel(const float* __restrict__ xs, const float2* __restrict__ tab,
                       unsigned* __restrict__ scratch, int n)
{
    const int lev = blockIdx.y;
    const int i   = blockIdx.x * 256 + threadIdx.x;
    if (i >= n) return;
    const int res = 16 << (3 + lev);
    const float2* __restrict__ tl = tab + kOff[3 + lev];

    const float px = xs[3 * i + 0];
    const float py = xs[3 * i + 1];
    const float pz = xs[3 * i + 2];

    const float fres = (float)res;
    float posx = px * fres, posy = py * fres, posz = pz * fres;
    float fxf = floorf(posx), fyf = floorf(posy), fzf = floorf(posz);
    float rx = posx - fxf, ry = posy - fyf, rz = posz - fzf;

    unsigned hx  = (unsigned)(int)fxf;
    unsigned hy0 = (unsigned)(int)fyf * 2654435761u, hy1 = hy0 + 2654435761u;
    unsigned hz0 = (unsigned)(int)fzf * 805459861u,  hz1 = hz0 + 805459861u;
    unsigned h00 = hy0 ^ hz0, h01 = hy0 ^ hz1, h10 = hy1 ^ hz0, h11 = hy1 ^ hz1;

    unsigned hx1 = hx + 1u;
    float2 v000 = tl[(hx ^ h00) & HMASK], v100 = tl[(hx1 ^ h00) & HMASK];
    float2 v001 = tl[(hx ^ h01) & HMASK], v101 = tl[(hx1 ^ h01) & HMASK];
    float2 v010 = tl[(hx ^ h10) & HMASK], v110 = tl[(hx1 ^ h10) & HMASK];
    float2 v011 = tl[(hx ^ h11) & HMASK], v111 = tl[(hx1 ^ h11) & HMASK];

    float wx1 = rx, wx0 = 1.f - rx;
    float wy1 = ry, wy0 = 1.f - ry;
    float wz1 = rz, wz0 = 1.f - rz;

    float f0, f1, w;
    w = wx0 * wy0 * wz0; f0  = w * v000.x; f1  = w * v000.y;
    w = wx0 * wy0 * wz1; f0 += w * v001.x; f1 += w * v001.y;
    w = wx0 * wy1 * wz0; f0 += w * v010.x; f1 += w * v010.y;
    w = wx0 * wy1 * wz1; f0 += w * v011.x; f1 += w * v011.y;
    w = wx1 * wy0 * wz0; f0 += w * v100.x; f1 += w * v100.y;
    w = wx1 * wy0 * wz1; f0 += w * v101.x; f1 += w * v101.y;
    w = wx1 * wy1 * wz0; f0 += w * v110.x; f1 += w * v110.y;
    w = wx1 * wy1 * wz1; f0 += w * v111.x; f1 += w * v111.y;

    unsigned packed = (__float_as_uint(f0) >> 16) | (__float_as_uint(f1) & 0xFFFF0000u);
    scratch[(size_t)lev * n + i] = packed;
}

// ---- final pass: dense levels 0-2 + merge + pos-enc-on-writeout ----
__global__ __launch_bounds__(BLK)
void final_kernel(const f4* __restrict__ xs4, const float* __restrict__ table,
                  const unsigned* __restrict__ scratch, float* __restrict__ out, int n)
{
    __shared__ float sbuf[BLK * SROW];
    const int tid  = threadIdx.x;
    const int base = blockIdx.x * BLK;
    const int pi   = base + tid;
    const bool val = (pi < n);

    // issue the 13 scratch loads first (plain loads -> L3 hits; independent)
    unsigned sc[NHASH];
    if (val) {
        #pragma unroll
        for (int h = 0; h < NHASH; ++h)
            sc[h] = scratch[(size_t)h * n + pi];
    }

    f4 pt = {0.f, 0.f, 0.f, 0.f};
    if (val) pt = xs4[pi];
    const float px = pt.x, py = pt.y, pz = pt.z;

    float* srow = sbuf + tid * SROW;
    const float2* __restrict__ tab = (const float2*)table;

    // dense levels 0..2 (tables total 2.5 MB -> cache-hot); idx(x1)=idx(x0)+1 always
    #pragma unroll
    for (int l = 0; l < 3; ++l) {
        const int res = 16 << l;
        const float2* __restrict__ tl = tab + kOff[l];
        const float fres = (float)res;

        float posx = px * fres, posy = py * fres, posz = pz * fres;
        float fxf = floorf(posx), fyf = floorf(posy), fzf = floorf(posz);
        float rx = posx - fxf, ry = posy - fyf, rz = posz - fzf;

        const unsigned r1 = (unsigned)(res + 1);
        const unsigned r2 = r1 * r1;
        unsigned x0 = (unsigned)(int)fxf;
        unsigned by0 = (unsigned)(int)fyf * r1; unsigned by1 = by0 + r1;
        unsigned cz0 = (unsigned)(int)fzf * r2; unsigned cz1 = cz0 + r2;

        float2 v000, v001, v010, v011, v100, v101, v110, v111;
        #define PAIRD(B, VA, VB) { \
            unsigned i0 = x0 + (B); \
            if ((i0 & 1u) == 0u) { f4 q = *(const f4*)(tl + i0); \
                VA.x = q.x; VA.y = q.y; VB.x = q.z; VB.y = q.w; } \
            else { VA = tl[i0]; VB = tl[i0 + 1u]; } }
        PAIRD(by0 + cz0, v000, v100)
        PAIRD(by0 + cz1, v001, v101)
        PAIRD(by1 + cz0, v010, v110)
        PAIRD(by1 + cz1, v011, v111)
        #undef PAIRD

        float wx1 = rx, wx0 = 1.f - rx;
        float wy1 = ry, wy0 = 1.f - ry;
        float wz1 = rz, wz0 = 1.f - rz;

        float f0, f1, w;
        w = wx0 * wy0 * wz0; f0  = w * v000.x; f1  = w * v000.y;
        w = wx0 * wy0 * wz1; f0 += w * v001.x; f1 += w * v001.y;
        w = wx0 * wy1 * wz0; f0 += w * v010.x; f1 += w * v010.y;
        w = wx0 * wy1 * wz1; f0 += w * v011.x; f1 += w * v011.y;
        w = wx1 * wy0 * wz0; f0 += w * v100.x; f1 += w * v100.y;
        w = wx1 * wy0 * wz1; f0 += w * v101.x; f1 += w * v101.y;
        w = wx1 * wy1 * wz0; f0 += w * v110.x; f1 += w * v110.y;
        w = wx1 * wy1 * wz1; f0 += w * v111.x; f1 += w * v111.y;

        srow[2 * l]     = f0;
        srow[2 * l + 1] = f1;
    }

    // hashed levels 3..15 (already loaded)
    #pragma unroll
    for (int h = 0; h < NHASH; ++h) {
        srow[6 + 2 * h] = __uint_as_float(sc[h] << 16);
        srow[7 + 2 * h] = __uint_as_float(sc[h] & 0xFFFF0000u);
    }
    srow[32] = px; srow[33] = py; srow[34] = pz;

    __syncthreads();

    // coalesced writeout; cols [35,71): g=f-35, freq=g/6, r=g%6,
    // val = (r<3 ? sin : cos)(xyz[r%3] * 2^freq)
    const int nvalid = min(BLK, n - base);
    float* obase = out + (size_t)base * 71;
    if (nvalid == BLK) {
        f4* o4 = (f4*)obase;
        #pragma unroll 1
        for (int i = tid; i < (BLK * 71) / 4; i += BLK) {
            const int e = 4 * i;
            f4 v;
            #pragma unroll
            for (int j = 0; j < 4; ++j) {
                const int ee = e + j;
                const int p = ee / 71;
                const int f = ee - p * 71;
                float valf;
                if (f < 35) {
                    valf = sbuf[p * SROW + f];
                } else {
                    const int g = f - 35;
                    const int freq = g / 6;
                    const int r = g - 6 * freq;
                    const int dim = (r < 3) ? r : r - 3;
                    const float a = sbuf[p * SROW + 32 + dim] * (float)(1 << freq);
                    float s, c;
                    __sincosf(a, &s, &c);
                    valf = (r < 3) ? s : c;
                }
                v[j] = valf;
            }
            __builtin_nontemporal_store(v, &o4[i]);
        }
    } else {
        #pragma unroll 1
        for (int i = tid; i < nvalid * 71; i += BLK) {
            const int p = i / 71;
            const int f = i - p * 71;
            float valf;
            if (f < 35) {
                valf = sbuf[p * SROW + f];
            } else {
                const int g = f - 35;
                const int freq = g / 6;
                const int r = g - 6 * freq;
                const int dim = (r < 3) ? r : r - 3;
                const float a = sbuf[p * SROW + 32 + dim] * (float)(1 << freq);
                float s, c;
                __sincosf(a, &s, &c);
                valf = (r < 3) ? s : c;
            }
            __builtin_nontemporal_store(valf, &obase[i]);
        }
    }
}

// fallback final (reads raw xs) for the ws-less path
__global__ __launch_bounds__(BLK)
void final_f32_kernel(const float* __restrict__ xs, const float* __restrict__ table,
                      const unsigned* __restrict__ scratch, float* __restrict__ out, int n)
{
    __shared__ float sbuf[BLK * SROW];
    const int tid  = threadIdx.x;
    const int base = blockIdx.x * BLK;
    const int pi   = base + tid;

    float px = 0.f, py = 0.f, pz = 0.f;
    if (pi < n) { px = xs[3*pi]; py = xs[3*pi+1]; pz = xs[3*pi+2]; }

    float* srow = sbuf + tid * SROW;
    const float2* __restrict__ tab = (const float2*)table;

    #pragma unroll
    for (int l = 0; l < 3; ++l) {
        const int res = 16 << l;
        const float2* __restrict__ tl = tab + kOff[l];
        const float fres = (float)res;
        float posx = px * fres, posy = py * fres, posz = pz * fres;
        float fxf = floorf(posx), fyf = floorf(posy), fzf = floorf(posz);
        float rx = posx - fxf, ry = posy - fyf, rz = posz - fzf;
        const unsigned r1 = (unsigned)(res + 1), r2 = r1 * r1;
        unsigned x0 = (unsigned)(int)fxf;
        unsigned by0 = (unsigned)(int)fyf * r1, by1 = by0 + r1;
        unsigned cz0 = (unsigned)(int)fzf * r2, cz1 = cz0 + r2;
        float2 v000 = tl[x0+by0+cz0], v100 = tl[x0+by0+cz0+1];
        float2 v001 = tl[x0+by0+cz1], v101 = tl[x0+by0+cz1+1];
        float2 v010 = tl[x0+by1+cz0], v110 = tl[x0+by1+cz0+1];
        float2 v011 = tl[x0+by1+cz1], v111 = tl[x0+by1+cz1+1];
        float wx1 = rx, wx0 = 1.f - rx, wy1 = ry, wy0 = 1.f - ry, wz1 = rz, wz0 = 1.f - rz;
        float f0, f1, w;
        w = wx0*wy0*wz0; f0  = w*v000.x; f1  = w*v000.y;
        w = wx0*wy0*wz1; f0 += w*v001.x; f1 += w*v001.y;
        w = wx0*wy1*wz0; f0 += w*v010.x; f1 += w*v010.y;
        w = wx0*wy1*wz1; f0 += w*v011.x; f1 += w*v011.y;
        w = wx1*wy0*wz0; f0 += w*v100.x; f1 += w*v100.y;
        w = wx1*wy0*wz1; f0 += w*v101.x; f1 += w*v101.y;
        w = wx1*wy1*wz0; f0 += w*v110.x; f1 += w*v110.y;
        w = wx1*wy1*wz1; f0 += w*v111.x; f1 += w*v111.y;
        srow[2*l] = f0; srow[2*l+1] = f1;
    }
    if (pi < n) {
        #pragma unroll
        for (int h = 0; h < NHASH; ++h) {
            unsigned u = scratch[(size_t)h * n + pi];
            srow[6+2*h] = __uint_as_float(u << 16);
            srow[7+2*h] = __uint_as_float(u & 0xFFFF0000u);
        }
    }
    srow[32] = px; srow[33] = py; srow[34] = pz;
    __syncthreads();
    const int nvalid = min(BLK, n - base);
    float* obase = out + (size_t)base * 71;
    #pragma unroll 1
    for (int i = tid; i < nvalid * 71; i += BLK) {
        const int p = i / 71;
        const int f = i - p * 71;
        float valf;
        if (f < 35) {
            valf = sbuf[p * SROW + f];
        } else {
            const int g = f - 35;
            const int freq = g / 6;
            const int r = g - 6 * freq;
            const int dim = (r < 3) ? r : r - 3;
            const float a = sbuf[p * SROW + 32 + dim] * (float)(1 << freq);
            float s, c;
            __sincosf(a, &s, &c);
            valf = (r < 3) ? s : c;
        }
        __builtin_nontemporal_store(valf, &obase[i]);
    }
}

extern "C" void kernel_launch(void* const* d_in, const int* in_sizes, int n_in,
                              void* d_out, int out_size, void* d_ws, size_t ws_size,
                              hipStream_t stream) {
    const float* xs    = (const float*)d_in[0];
    const float* table = (const float*)d_in[1];
    float* out = (float*)d_out;
    const int n = in_sizes[0] / 3;          // 2,000,000 points

    unsigned* scratch = (unsigned*)d_ws;                       // 13*n*4 = 104 MB
    const size_t featBytes = (size_t)NHASH * (size_t)n * 4u;
    const size_t tblBytes  = (size_t)NHASH * HSIZE * 4u;       // 27.3 MB
    const size_t xs4Bytes  = (size_t)n * 16u;                  // 32 MB
    const float2* tab = (const float2*)table;
    const int gf = (n + BLK - 1) / BLK;

    if (ws_size >= featBytes + tblBytes + xs4Bytes) {
        unsigned* tbf = (unsigned*)((char*)d_ws + featBytes);
        f4* xs4 = (f4*)((char*)d_ws + featBytes + tblBytes);

        const int packBlocks = (n + 255) / 256;
        hipLaunchKernelGGL(prep_kernel, dim3(CONV_BLOCKS + packBlocks), dim3(256),
                           0, stream, xs, tab, tbf, xs4, n);

        const int bpl = (n + 511) / 512;
        hipLaunchKernelGGL(levels_kernel, dim3(bpl, NHASH), dim3(256), 0, stream,
                           xs4, tbf, scratch, n);
        hipLaunchKernelGGL(final_kernel, dim3(gf), dim3(BLK), 0, stream,
                           xs4, table, scratch, out, n);
    } else {
        const int bpl = (n + 255) / 256;
        hipLaunchKernelGGL(levels_f32_kernel, dim3(bpl, NHASH), dim3(256), 0, stream,
                           xs, tab, scratch, n);
        hipLaunchKernelGGL(final_f32_kernel, dim3(gf), dim3(BLK), 0, stream,
                           xs, table, scratch, out, n);
    }
}